// Round 1
// baseline (2275.822 us; speedup 1.0000x reference)
//
#include <hip/hip_runtime.h>
#include <hip/hip_bf16.h>

#define B_ 16
#define C_ 64
#define T_ 30
#define H_ 64
#define W_ 44
#define HW_ (H_*W_)          // 2816
#define THW_ (T_*HW_)        // 84480

typedef __bf16 bf16x8 __attribute__((ext_vector_type(8)));
typedef float f32x4 __attribute__((ext_vector_type(4)));

static __device__ __forceinline__ short f2bf(float f) {
    __hip_bfloat16 h = __float2bfloat16(f);
    union { __hip_bfloat16 b; short s; } u; u.b = h; return u.s;
}

// ---------------- kernel 1: global average pool ----------------
// grid = B*C blocks, one (b,c) plane each (84480 contiguous floats)
__global__ __launch_bounds__(256) void gap_kernel(const float* __restrict__ x,
                                                  float* __restrict__ gap) {
    int bc = blockIdx.x;
    const float4* p4 = (const float4*)(x + (size_t)bc * THW_);
    float sum = 0.f;
    for (int i = threadIdx.x; i < THW_ / 4; i += 256) {
        float4 v = p4[i];
        sum += (v.x + v.y) + (v.z + v.w);
    }
    #pragma unroll
    for (int o = 32; o > 0; o >>= 1) sum += __shfl_down(sum, o);
    __shared__ float partial[4];
    if ((threadIdx.x & 63) == 0) partial[threadIdx.x >> 6] = sum;
    __syncthreads();
    if (threadIdx.x == 0)
        gap[bc] = (partial[0] + partial[1] + partial[2] + partial[3]) * (1.0f / THW_);
}

// ---------------- kernel 2: reduce FC + fc1 + sigmoid ----------------
__global__ __launch_bounds__(256) void fc_kernel(const float* __restrict__ gap,
        const float* __restrict__ w_reduce, const float* __restrict__ b_reduce,
        const float* __restrict__ w_fc1, const float* __restrict__ b_fc1,
        float* __restrict__ h_out) {
    __shared__ float gl[256];                 // g[16 b][16 j]
    int t = threadIdx.x;
    {
        int b = t >> 4, j = t & 15;
        float a = b_reduce[j];
        #pragma unroll
        for (int c = 0; c < 64; ++c) a += gap[b*64 + c] * w_reduce[j*64 + c];
        gl[b*16 + j] = a;
    }
    __syncthreads();
    for (int idx = t; idx < 2048; idx += 256) {
        int b = idx >> 7, j = idx & 127;
        float v = b_fc1[j];
        #pragma unroll
        for (int i = 0; i < 16; ++i) v += gl[b*16 + i] * w_fc1[j*16 + i];
        h_out[idx] = 1.0f / (1.0f + expf(-v));
    }
}

// ---------------- kernel 3: expand dynamic weights to bf16 ----------------
// layout: wdyn[b][tap(27)][oc(64)][ic(64)]  (tap-major for conv staging)
__global__ __launch_bounds__(256) void wdyn_kernel(const float* __restrict__ w_fc2,
        const float* __restrict__ h, short* __restrict__ wdyn) {
    int b = blockIdx.x / 27, tap = blockIdx.x % 27;
    short* dst = wdyn + ((size_t)b*27 + tap) * 4096;
    for (int e = threadIdx.x; e < 4096; e += 256) {
        int oc = e >> 6, ic = e & 63;
        float wv = w_fc2[(oc*64 + ic)*27 + tap];   // flat = oc*1728+ic*27+tap = g*864+o
        float hv = h[b*128 + 2*oc + (ic >> 5)];    // group g = 2*oc + (ic>=32)
        dst[e] = f2bf(wv * hv);
    }
}

// ---------------- kernel 4: implicit-GEMM dynamic conv3d ----------------
// block = 128 thr (2 waves); tile: 64 oc x (tz=2, ty=8, tx=16) = 256 positions
// wave w handles t-slice dz=w: 64oc x 128pos = 4 Mtiles x 8 Ntiles of 16x16x32
__global__ __launch_bounds__(128, 1) void conv_kernel(const float* __restrict__ x,
        const short* __restrict__ wdyn, float* __restrict__ out) {
    __shared__ short xs[720*40];   // x tile [s=4*10*18][32 ic] rows padded to 80 B
    __shared__ short wb[64*40];    // weights [64 oc][32 ic]   rows padded to 80 B

    int bid = blockIdx.x;
    int b = bid / 360; int r = bid - b*360;
    int tz = r / 24;  r -= tz*24;
    int ty = r / 3;   int tx = r - ty*3;

    int tid  = threadIdx.x;
    int wave = tid >> 6;
    int lane = tid & 63;
    int ln = lane & 15, kg = lane >> 4;

    const float* xb  = x    + (size_t)b * C_ * THW_;
    const short* wdb = wdyn + (size_t)b * 27 * 4096;

    f32x4 acc[4][8];
    #pragma unroll
    for (int mt = 0; mt < 4; ++mt)
        #pragma unroll
        for (int j = 0; j < 8; ++j) acc[mt][j] = f32x4{0.f, 0.f, 0.f, 0.f};

    int woc = tid >> 1, wseg = tid & 1;       // weight stage: 32 B per thread
    uint4 wr0, wr1;
    {
        const uint4* src = (const uint4*)(wdb + woc*64 + wseg*16);
        wr0 = src[0]; wr1 = src[1];
    }

    for (int half = 0; half < 2; ++half) {
        int c0 = half * 32;
        __syncthreads();                       // xs safe to overwrite
        // ---- stage x tile (fp32 -> bf16), zero-padded halo ----
        for (int e = tid; e < 23040; e += 128) {   // 32 ic * 720 spatial
            int ic = e / 720; int s = e - ic*720;
            int z  = s / 180; int r2 = s - z*180;
            int y  = r2 / 18; int xx = r2 - y*18;
            int t  = tz*2  + z  - 1;
            int hh = ty*8  + y  - 1;
            int ww = tx*16 + xx - 1;
            float v = 0.f;
            if ((unsigned)t < (unsigned)T_ && (unsigned)hh < (unsigned)H_ &&
                (unsigned)ww < (unsigned)W_)
                v = xb[(size_t)(c0+ic)*THW_ + t*HW_ + hh*W_ + ww];
            xs[s*40 + ic] = f2bf(v);
        }
        for (int tap = 0; tap < 27; ++tap) {
            __syncthreads();                   // prev tap's wb reads done; xs staged
            *(uint4*)&wb[woc*40 + wseg*16]     = wr0;
            *(uint4*)&wb[woc*40 + wseg*16 + 8] = wr1;
            int step = half*27 + tap + 1;      // prefetch next tap's weights
            if (step < 54) {
                int ntap = step % 27; int nc0 = (step / 27) * 32;
                const uint4* src = (const uint4*)(wdb + ntap*4096 + woc*64 + nc0 + wseg*16);
                wr0 = src[0]; wr1 = src[1];
            }
            __syncthreads();                   // wb visible
            int kd = tap / 9; int kh = (tap / 3) % 3; int kw = tap - kd*9 - kh*3;
            bf16x8 a[4];
            #pragma unroll
            for (int mt = 0; mt < 4; ++mt)
                a[mt] = *(const bf16x8*)&wb[(mt*16 + ln)*40 + kg*8];
            int zb = wave + kd;
            #pragma unroll
            for (int j = 0; j < 8; ++j) {
                int s = (zb*10 + (j + kh))*18 + (ln + kw);
                bf16x8 bv = *(const bf16x8*)&xs[s*40 + kg*8];
                acc[0][j] = __builtin_amdgcn_mfma_f32_16x16x32_bf16(a[0], bv, acc[0][j], 0, 0, 0);
                acc[1][j] = __builtin_amdgcn_mfma_f32_16x16x32_bf16(a[1], bv, acc[1][j], 0, 0, 0);
                acc[2][j] = __builtin_amdgcn_mfma_f32_16x16x32_bf16(a[2], bv, acc[2][j], 0, 0, 0);
                acc[3][j] = __builtin_amdgcn_mfma_f32_16x16x32_bf16(a[3], bv, acc[3][j], 0, 0, 0);
            }
        }
    }
    // ---- epilogue: D layout col=lane&15, row=(lane>>4)*4+ri ----
    int t    = tz*2  + wave;
    int wout = tx*16 + ln;
    if (wout < W_) {
        #pragma unroll
        for (int mt = 0; mt < 4; ++mt)
            #pragma unroll
            for (int j = 0; j < 8; ++j) {
                int hh = ty*8 + j;
                float* o = out + ((size_t)(b*64 + mt*16 + kg*4)*T_ + t)*HW_ + hh*W_ + wout;
                #pragma unroll
                for (int ri = 0; ri < 4; ++ri)
                    o[(size_t)ri * THW_] = acc[mt][j][ri];
            }
    }
}

extern "C" void kernel_launch(void* const* d_in, const int* in_sizes, int n_in,
                              void* d_out, int out_size, void* d_ws, size_t ws_size,
                              hipStream_t stream) {
    const float* x        = (const float*)d_in[0];
    const float* w_reduce = (const float*)d_in[1];
    const float* b_reduce = (const float*)d_in[2];
    const float* w_fc1    = (const float*)d_in[3];
    const float* b_fc1    = (const float*)d_in[4];
    const float* w_fc2    = (const float*)d_in[5];
    float* out = (float*)d_out;

    float* gap  = (float*)d_ws;            // 1024 floats
    float* h    = gap + 1024;              // 2048 floats
    short* wdyn = (short*)(h + 2048);      // 16*27*4096 bf16 = 3.4 MB

    gap_kernel <<<B_*C_, 256, 0, stream>>>(x, gap);
    fc_kernel  <<<1,     256, 0, stream>>>(gap, w_reduce, b_reduce, w_fc1, b_fc1, h);
    wdyn_kernel<<<B_*27, 256, 0, stream>>>(w_fc2, h, wdyn);
    conv_kernel<<<B_*360, 128, 0, stream>>>(x, wdyn, out);
}

// Round 2
// 607.161 us; speedup vs baseline: 3.7483x; 3.7483x over previous
//
#include <hip/hip_runtime.h>
#include <hip/hip_bf16.h>
#include <stdint.h>

#define B_ 16
#define T_ 30
#define H_ 64
#define W_ 44
#define HW_ (H_*W_)            // 2816
#define THW_ (T_*HW_)          // 84480

// padded transposed layout: xt[b][half][t:30][hp:66][wp:46][32 ic] bf16
#define HP_ 66
#define WP_ 46
#define PPLANE_ (HP_*WP_)      // 3036
#define PPOS_ (T_*PPLANE_)     // 91080 pos per (b,half)

// conv tiling: block = 256 thr (4 waves), out tile 4t x 8h x 16w, 64 oc
#define TZ 4
#define TY 8
#define TX 16
#define SZ 6
#define SY 10
#define SX 18
#define NS (SZ*SY*SX)          // 1080 staged spatial rows (64 B each per K-half)

typedef __bf16 bf16x8 __attribute__((ext_vector_type(8)));
typedef float f32x4 __attribute__((ext_vector_type(4)));

static __device__ __forceinline__ short f2bf(float f) {
    __hip_bfloat16 h = __float2bfloat16(f);
    union { __hip_bfloat16 b; short s; } u; u.b = h; return u.s;
}

static __device__ __forceinline__ void gload_lds16(const short* g, short* l) {
    __builtin_amdgcn_global_load_lds((const __attribute__((address_space(1))) void*)g,
                                     (__attribute__((address_space(3))) void*)l, 16, 0, 0);
}

// ---------------- kernel 0: transpose x -> padded channel-fastest bf16 ----------------
__global__ __launch_bounds__(256) void transpose_kernel(const float* __restrict__ x,
                                                        short* __restrict__ xt) {
    __shared__ short lb[64*52];            // [ic][w], rows padded to 52 shorts
    int blk = blockIdx.x;
    int b = blk / (T_*HP_);
    int r = blk - b*(T_*HP_);
    int t = r / HP_;
    int hp = r - t*HP_;
    int tid = threadIdx.x;
    bool interior = (hp >= 1) && (hp <= H_);
    if (interior) {
        int h = hp - 1;
        for (int e = tid; e < 704; e += 256) {        // 64 ic x 11 float4
            int ic = e / 11, q = e - ic*11;
            const float4* p = (const float4*)(x + ((size_t)(b*64 + ic)*T_ + t)*HW_ + h*W_) + q;
            float4 v = *p;
            short4 s4;
            s4.x = f2bf(v.x); s4.y = f2bf(v.y); s4.z = f2bf(v.z); s4.w = f2bf(v.w);
            *(short4*)&lb[ic*52 + q*4] = s4;
        }
    }
    __syncthreads();
    for (int e = tid; e < WP_*16; e += 256) {         // 46 wp x 16 (4 ic each)
        int wp = e >> 4, i4 = (e & 15) * 4;
        short4 s4 = make_short4(0,0,0,0);
        if (interior && wp >= 1 && wp <= W_) {
            int w = wp - 1;
            s4.x = lb[(i4+0)*52 + w];
            s4.y = lb[(i4+1)*52 + w];
            s4.z = lb[(i4+2)*52 + w];
            s4.w = lb[(i4+3)*52 + w];
        }
        size_t pos = (size_t)t*PPLANE_ + hp*WP_ + wp;
        short* dst = xt + ((size_t)(b*2 + (i4 >> 5))*PPOS_ + pos)*32 + (i4 & 31);
        *(short4*)dst = s4;
    }
}

// ---------------- kernel 1: global average pool ----------------
__global__ __launch_bounds__(256) void gap_kernel(const float* __restrict__ x,
                                                  float* __restrict__ gap) {
    int bc = blockIdx.x;
    const float4* p4 = (const float4*)(x + (size_t)bc * THW_);
    float sum = 0.f;
    for (int i = threadIdx.x; i < THW_ / 4; i += 256) {
        float4 v = p4[i];
        sum += (v.x + v.y) + (v.z + v.w);
    }
    #pragma unroll
    for (int o = 32; o > 0; o >>= 1) sum += __shfl_down(sum, o);
    __shared__ float partial[4];
    if ((threadIdx.x & 63) == 0) partial[threadIdx.x >> 6] = sum;
    __syncthreads();
    if (threadIdx.x == 0)
        gap[bc] = (partial[0] + partial[1] + partial[2] + partial[3]) * (1.0f / THW_);
}

// ---------------- kernel 2: reduce FC + fc1 + sigmoid ----------------
__global__ __launch_bounds__(256) void fc_kernel(const float* __restrict__ gap,
        const float* __restrict__ w_reduce, const float* __restrict__ b_reduce,
        const float* __restrict__ w_fc1, const float* __restrict__ b_fc1,
        float* __restrict__ h_out) {
    __shared__ float gl[256];
    int t = threadIdx.x;
    {
        int b = t >> 4, j = t & 15;
        float a = b_reduce[j];
        #pragma unroll
        for (int c = 0; c < 64; ++c) a += gap[b*64 + c] * w_reduce[j*64 + c];
        gl[b*16 + j] = a;
    }
    __syncthreads();
    for (int idx = t; idx < 2048; idx += 256) {
        int b = idx >> 7, j = idx & 127;
        float v = b_fc1[j];
        #pragma unroll
        for (int i = 0; i < 16; ++i) v += gl[b*16 + i] * w_fc1[j*16 + i];
        h_out[idx] = 1.0f / (1.0f + expf(-v));
    }
}

// ---------------- kernel 3: dynamic weights bf16 (+ zero block) ----------------
__global__ __launch_bounds__(256) void wdyn_kernel(const float* __restrict__ w_fc2,
        const float* __restrict__ h, short* __restrict__ wdyn, short* __restrict__ zblk) {
    if (blockIdx.x == 0 && threadIdx.x < 128) zblk[threadIdx.x] = 0;
    int b = blockIdx.x / 27, tap = blockIdx.x % 27;
    short* dst = wdyn + ((size_t)b*27 + tap) * 4096;
    for (int e = threadIdx.x; e < 4096; e += 256) {
        int oc = e >> 6, ic = e & 63;
        float wv = w_fc2[(oc*64 + ic)*27 + tap];
        float hv = h[b*128 + 2*oc + (ic >> 5)];
        dst[e] = f2bf(wv * hv);
    }
}

// ---------------- kernel 4: implicit-GEMM dynamic conv3d ----------------
__global__ __launch_bounds__(256, 2) void conv_kernel(const short* __restrict__ xt,
        const short* __restrict__ wdyn, const short* __restrict__ zblk,
        float* __restrict__ out) {
    __shared__ short xs[NS*32 + 256];      // 69,632 B
    __shared__ short wb[2][2048];          // 2 x 4 KB

    int bid = blockIdx.x;
    int b = bid / 192; int r = bid - b*192;
    int tzt = r / 24; r -= tzt*24;
    int tyt = r / 3;  int txt = r - tyt*3;
    int t0 = tzt*TZ, h0 = tyt*TY, w0 = txt*TX;

    int tid = threadIdx.x, wid = tid >> 6, lane = tid & 63;
    int ln = lane & 15, kg = lane >> 4;
    int l4 = lane >> 2, c = lane & 3;

    const short* wdb = wdyn + (size_t)b * 27 * 4096;

    f32x4 acc[4][8];
    #pragma unroll
    for (int mt = 0; mt < 4; ++mt)
        #pragma unroll
        for (int j = 0; j < 8; ++j) acc[mt][j] = f32x4{0.f, 0.f, 0.f, 0.f};

    auto stage_w = [&](int step) {
        int tap = step % 27, half = step / 27;
        const short* base = wdb + tap*4096 + half*32;
        short* dst = wb[step & 1];
        #pragma unroll
        for (int jj = 0; jj < 4; ++jj) {
            int oc = jj*16 + l4;
            gload_lds16(base + oc*64 + ((c ^ (oc & 3)) * 8), dst + jj*512);
        }
    };
    auto stage_x = [&](int half) {
        const short* xbh = xt + (size_t)(b*2 + half) * PPOS_ * 32;
        #pragma unroll 2
        for (int ii = 0; ii < 17; ++ii) {
            int inst = wid*17 + ii;
            int s = inst*16 + l4;
            int z = s / 180; int rr = s - z*180;
            int y = rr / 18; int xx = rr - y*18;
            int t = t0 + z - 1;
            int seg = (c ^ (s & 3)) * 8;
            const short* src = ((unsigned)t < (unsigned)T_)
                ? xbh + ((size_t)t*PPLANE_ + (h0+y)*WP_ + (w0+xx))*32 + seg
                : zblk + seg;
            gload_lds16(src, xs + inst*512);
        }
    };

    stage_x(0);
    if (wid == 0) stage_w(0);
    __syncthreads();

    for (int step = 0; step < 54; ++step) {
        int nstep = step + 1;
        if (nstep < 54 && wid == (nstep & 3)) stage_w(nstep);

        int tap = step % 27;
        int kd = tap / 9; int rr = tap - kd*9; int kh = rr / 3; int kw = rr - kh*3;
        const short* wbp = wb[step & 1];
        bf16x8 a[4];
        #pragma unroll
        for (int mt = 0; mt < 4; ++mt) {
            int oc = mt*16 + ln;
            a[mt] = *(const bf16x8*)&wbp[oc*32 + ((kg ^ (oc & 3)) * 8)];
        }
        int sb = (wid + kd)*180 + kh*18 + kw + ln;
        #pragma unroll
        for (int j = 0; j < 8; ++j) {
            int s = sb + j*18;
            bf16x8 bv = *(const bf16x8*)&xs[s*32 + ((kg ^ (s & 3)) * 8)];
            acc[0][j] = __builtin_amdgcn_mfma_f32_16x16x32_bf16(a[0], bv, acc[0][j], 0, 0, 0);
            acc[1][j] = __builtin_amdgcn_mfma_f32_16x16x32_bf16(a[1], bv, acc[1][j], 0, 0, 0);
            acc[2][j] = __builtin_amdgcn_mfma_f32_16x16x32_bf16(a[2], bv, acc[2][j], 0, 0, 0);
            acc[3][j] = __builtin_amdgcn_mfma_f32_16x16x32_bf16(a[3], bv, acc[3][j], 0, 0, 0);
        }
        __syncthreads();
        if (step == 26) { stage_x(1); __syncthreads(); }
    }

    int t = t0 + wid;
    int wv = w0 + ln;
    if (t < T_ && wv < W_) {
        #pragma unroll
        for (int mt = 0; mt < 4; ++mt) {
            size_t obase = ((size_t)(b*64 + mt*16 + kg*4) * T_ + t) * HW_;
            #pragma unroll
            for (int j = 0; j < 8; ++j) {
                float* o = out + obase + (h0 + j)*W_ + wv;
                #pragma unroll
                for (int ri = 0; ri < 4; ++ri)
                    o[(size_t)ri * THW_] = acc[mt][j][ri];
            }
        }
    }
}

extern "C" void kernel_launch(void* const* d_in, const int* in_sizes, int n_in,
                              void* d_out, int out_size, void* d_ws, size_t ws_size,
                              hipStream_t stream) {
    const float* x        = (const float*)d_in[0];
    const float* w_reduce = (const float*)d_in[1];
    const float* b_reduce = (const float*)d_in[2];
    const float* w_fc1    = (const float*)d_in[3];
    const float* b_fc1    = (const float*)d_in[4];
    const float* w_fc2    = (const float*)d_in[5];
    float* out = (float*)d_out;

    // ws layout: gap 4KB | h 8KB | wdyn 3.375MB | zblk 256B | xt 186.5MB (+slack)
    float* gap  = (float*)d_ws;
    float* h    = gap + 1024;
    short* wdyn = (short*)(h + 2048);
    short* zblk = wdyn + (size_t)B_*27*4096;
    short* xt   = zblk + 128;

    transpose_kernel<<<B_*T_*HP_, 256, 0, stream>>>(x, xt);
    gap_kernel      <<<B_*64,     256, 0, stream>>>(x, gap);
    fc_kernel       <<<1,         256, 0, stream>>>(gap, w_reduce, b_reduce, w_fc1, b_fc1, h);
    wdyn_kernel     <<<B_*27,     256, 0, stream>>>(w_fc2, h, wdyn, zblk);
    conv_kernel     <<<B_*192,    256, 0, stream>>>(xt, wdyn, zblk, out);
}